// Round 6
// baseline (2716.800 us; speedup 1.0000x reference)
//
#include <hip/hip_runtime.h>
#include <math.h>

#define Bb     32
#define NVv    400
#define Mm     512
#define Kk     32
#define Nn     501
#define MAXIT  10
#define EPSd   1e-12f
#define NT     512

typedef float v2f __attribute__((ext_vector_type(2)));

// DPP-based float add-combine: x += dpp_perm(x). Masked-off rows add old=0.
#define DPP_ADD(x, ctrl, rmask)                                                        \
    (x) += __int_as_float(__builtin_amdgcn_update_dpp(                                 \
              0, __float_as_int(x), (ctrl), (rmask), 0xF, false))

#define QUAD_PERM_X1 0xB1   // [1,0,3,2]  xor-1
#define QUAD_PERM_X2 0x4E   // [2,3,0,1]  xor-2
#define ROW_HALF_MIR 0x141  // xor-4 (quads uniform)
#define ROW_MIR      0x140  // xor-8 (8-groups uniform)
#define ROW_BCAST15  0x142  // row r+1 gets row r's lane 15
#define ROW_BCAST31  0x143  // rows 2,3 get lane 31

// full 64-lane sum; total valid in row 3 (lanes 48-63)
#define REDUCE64(x)                 \
    DPP_ADD(x, QUAD_PERM_X1, 0xF);  \
    DPP_ADD(x, QUAD_PERM_X2, 0xF);  \
    DPP_ADD(x, ROW_HALF_MIR, 0xF);  \
    DPP_ADD(x, ROW_MIR,      0xF);  \
    DPP_ADD(x, ROW_BCAST15,  0xA);  \
    DPP_ADD(x, ROW_BCAST31,  0xC)

// Barrier that does NOT drain vmcnt: orders LDS (lgkmcnt) only, so the
// S-row prefetch global_loads stay in flight across the barrier (T4 idiom).
// asm memory clobbers = compiler fences on both sides of the raw s_barrier.
#define BLOCK_SYNC_LDS()                                           \
    do {                                                           \
        asm volatile("s_waitcnt lgkmcnt(0)" ::: "memory");         \
        __builtin_amdgcn_s_barrier();                              \
        asm volatile("" ::: "memory");                             \
    } while (0)

__global__ void __launch_bounds__(NT, 1)
satnet_kernel(const float* __restrict__ S, const float* __restrict__ z,
              const int* __restrict__ isin, const float* __restrict__ Vinit,
              const int* __restrict__ perm, float* __restrict__ out)
{
    __shared__ __align__(16) float V_lds[Nn * Kk];   // 64128 B: V[n][k], slice [4w,4w+4) owned by wave w
    __shared__ float z_lds[Nn];
    __shared__ int   inp_lds[Nn];
    __shared__ float sn_lds[Nn];
    __shared__ int   permc[Nn - 1];
    __shared__ float v0_lds[Kk];
    __shared__ __align__(16) float gred[2][8][4];
    __shared__ __align__(16) float qred[2][8];
    __shared__ int   cnt_lds;

    const int b    = blockIdx.x;
    const int t    = threadIdx.x;
    const int lane = t & 63;
    const int w    = t >> 6;          // wave id: owns k in [4w, 4w+4)
    const int m0   = lane << 2;       // 4 m's in [0,256)
    const int m1   = 256 + (lane << 2);
    const float PI_F = 3.14159274101257324f;

    // ---------- phase 0: z_full / inp / Snrms ----------
    if (t < Nn) {
        float zv; int iv;
        if (t == 0)        { zv = 1.f;                iv = 1; }
        else if (t <= NVv) { zv = z[b * NVv + t - 1]; iv = isin[b * NVv + t - 1]; }
        else               { zv = 0.f;                iv = 0; }
        z_lds[t]   = zv;
        inp_lds[t] = (iv > 0) ? 1 : 0;

        const float4* row = (const float4*)(S + (size_t)t * Mm);
        float a0 = 0.f, a1 = 0.f, a2 = 0.f, a3 = 0.f;
        #pragma unroll 4
        for (int j = 0; j < Mm / 4; ++j) {
            float4 v = row[j];
            a0 += v.x * v.x; a1 += v.y * v.y; a2 += v.z * v.z; a3 += v.w * v.w;
        }
        sn_lds[t] = (a0 + a1) + (a2 + a3);
    }
    __syncthreads();

    // ---------- phase 1: V normalize + pin ----------
    {
        const int r   = t >> 5;   // 0..15
        const int kk2 = t & 31;   // k

        if (t < 32) {  // row 0 -> v0
            float v = Vinit[((size_t)b * Nn) * Kk + t];
            float q = v * v;
            q += __shfl_xor(q, 1, 32); q += __shfl_xor(q, 2, 32);
            q += __shfl_xor(q, 4, 32); q += __shfl_xor(q, 8, 32);
            q += __shfl_xor(q, 16, 32);
            float nv = v / fmaxf(sqrtf(q), EPSd);
            v0_lds[t] = nv;
            V_lds[t] = nv;
        }
        __syncthreads();
        float v0k = v0_lds[kk2];

        for (int it = 0; it < 32; ++it) {
            int n = 1 + it * 16 + r;
            if (n <= 500) {
                float v = Vinit[((size_t)b * Nn + n) * Kk + kk2];
                float q = v * v;
                q += __shfl_xor(q, 1, 32); q += __shfl_xor(q, 2, 32);
                q += __shfl_xor(q, 4, 32); q += __shfl_xor(q, 8, 32);
                q += __shfl_xor(q, 16, 32);
                float nv = v / fmaxf(sqrtf(q), EPSd);
                float res = nv;
                if (inp_lds[n]) {
                    float d = nv * v0k;
                    d += __shfl_xor(d, 1, 32); d += __shfl_xor(d, 2, 32);
                    d += __shfl_xor(d, 4, 32); d += __shfl_xor(d, 8, 32);
                    d += __shfl_xor(d, 16, 32);
                    float vp = nv - d * v0k;
                    float q2 = vp * vp;
                    q2 += __shfl_xor(q2, 1, 32); q2 += __shfl_xor(q2, 2, 32);
                    q2 += __shfl_xor(q2, 4, 32); q2 += __shfl_xor(q2, 8, 32);
                    q2 += __shfl_xor(q2, 16, 32);
                    vp = vp / fmaxf(sqrtf(q2), EPSd);
                    float ang = PI_F * z_lds[n];
                    res = -cosf(ang) * v0k + sinf(ang) * vp;
                }
                V_lds[n * Kk + kk2] = res;
            }
        }
    }
    __syncthreads();

    // ---------- phase 2: compact perm (pinned coords are exact no-ops) ----------
    if (w == 0) {
        int cnt = 0;
        for (int base = 0; base < Nn - 1; base += 64) {
            int idx = base + lane;
            int iv = 0; bool keep = false;
            if (idx < Nn - 1) { iv = perm[idx]; keep = (inp_lds[iv] == 0); }
            unsigned long long mk = __ballot(keep);
            int pos = cnt + (int)__popcll(mk & ((1ull << lane) - 1ull));
            if (keep) permc[pos] = iv;
            cnt += (int)__popcll(mk);
        }
        if (lane == 0) cnt_lds = cnt;
    }
    __syncthreads();
    const int cnt = cnt_lds;

    // ---------- phase 3: W init (transposed ownership, packed f32) ----------
    // w2[kk][j]: W[4w+kk][ m0+2j, m0+2j+1 ] for j<2 ; [ m1+2(j-2), ... ] for j>=2
    v2f w2[4][4];
    {
        v2f zz; zz.x = 0.f; zz.y = 0.f;
        #pragma unroll
        for (int kk = 0; kk < 4; ++kk)
            #pragma unroll
            for (int j = 0; j < 4; ++j) w2[kk][j] = zz;
    }

    #pragma unroll 2
    for (int n = 0; n < Nn; ++n) {
        float4 v4 = *(const float4*)&V_lds[n * Kk + (w << 2)];   // wave-uniform broadcast
        float4 s0 = *(const float4*)&S[(size_t)n * Mm + m0];
        float4 s1 = *(const float4*)&S[(size_t)n * Mm + m1];
        v2f s2[4] = { {s0.x, s0.y}, {s0.z, s0.w}, {s1.x, s1.y}, {s1.z, s1.w} };
        v2f vb[4] = { {v4.x, v4.x}, {v4.y, v4.y}, {v4.z, v4.z}, {v4.w, v4.w} };
        #pragma unroll
        for (int kk = 0; kk < 4; ++kk)
            #pragma unroll
            for (int j = 0; j < 4; ++j)
                w2[kk][j] += vb[kk] * s2[j];     // -> v_pk_fma_f32
    }

    // ---------- main loop ----------
    if (cnt > 0) {
        int si = 0;
        int i  = permc[0];
        // current s row in registers (direct from global; L1-broadcast across waves)
        float4 sa0 = *(const float4*)&S[(size_t)i * Mm + m0];
        float4 sa1 = *(const float4*)&S[(size_t)i * Mm + m1];
        float4 vold4 = *(const float4*)&V_lds[i * Kk + (w << 2)];

        const int total = MAXIT * cnt;
        for (int step = 0; step < total; ++step) {
            int sin_ = si + 1; if (sin_ == cnt) sin_ = 0;
            const int inext = permc[sin_];
            // prefetch next step's s row (global; stays in flight across the
            // lgkm-only barrier below) and next v_old (LDS, own slice)
            float4 sp0    = *(const float4*)&S[(size_t)inext * Mm + m0];
            float4 sp1    = *(const float4*)&S[(size_t)inext * Mm + m1];
            float4 vnext4 = *(const float4*)&V_lds[inext * Kk + (w << 2)];
            float  sni    = sn_lds[i];

            v2f s2[4] = { {sa0.x, sa0.y}, {sa0.z, sa0.w}, {sa1.x, sa1.y}, {sa1.z, sa1.w} };

            // gemv partials: p[kk] = W[4w+kk][my m's] . s[my m's]  (packed f32)
            float p[4];
            #pragma unroll
            for (int kk = 0; kk < 4; ++kk) {
                v2f acc = w2[kk][0] * s2[0];
                acc += w2[kk][1] * s2[1];
                acc += w2[kk][2] * s2[2];
                acc += w2[kk][3] * s2[3];
                p[kk] = acc.x + acc.y;
            }

            // 64-lane sums (VALU-only DPP); totals valid in row 3
            REDUCE64(p[0]); REDUCE64(p[1]); REDUCE64(p[2]); REDUCE64(p[3]);

            const int par = step & 1;
            if (lane == 63) {
                float g0 = p[0] - sni * vold4.x;
                float g1 = p[1] - sni * vold4.y;
                float g2 = p[2] - sni * vold4.z;
                float g3 = p[3] - sni * vold4.w;
                *(float4*)&gred[par][w][0] = make_float4(g0, g1, g2, g3);
                qred[par][w] = (g0 * g0 + g1 * g1) + (g2 * g2 + g3 * g3);
            }
            // lgkm-only barrier: orders the gred/qred ds_writes vs the reads
            // below WITHOUT draining the global prefetch (no vmcnt(0) here).
            BLOCK_SYNC_LDS();

            float4 g4 = *(const float4*)&gred[par][w][0];
            float4 qa = *(const float4*)&qred[par][0];
            float4 qb = *(const float4*)&qred[par][4];
            float gn2  = ((qa.x + qa.y) + (qa.z + qa.w)) + ((qb.x + qb.y) + (qb.z + qb.w));
            float rden = -1.0f / fmaxf(sqrtf(gn2), EPSd);
            float4 vnew4, dv4;
            vnew4.x = g4.x * rden; vnew4.y = g4.y * rden;
            vnew4.z = g4.z * rden; vnew4.w = g4.w * rden;
            dv4.x = vnew4.x - vold4.x; dv4.y = vnew4.y - vold4.y;
            dv4.z = vnew4.z - vold4.z; dv4.w = vnew4.w - vold4.w;
            // write-back: only this wave ever touches slice [4w,4w+4) of V
            if (lane == 0) *(float4*)&V_lds[i * Kk + (w << 2)] = vnew4;

            v2f dvb[4] = { {dv4.x, dv4.x}, {dv4.y, dv4.y}, {dv4.z, dv4.z}, {dv4.w, dv4.w} };
            #pragma unroll
            for (int kk = 0; kk < 4; ++kk)
                #pragma unroll
                for (int j = 0; j < 4; ++j)
                    w2[kk][j] += dvb[kk] * s2[j];   // -> v_pk_fma_f32

            if (cnt == 1) {  // same coordinate repeats: prefetched v_old is stale
                vold4 = vnew4;
            } else {
                vold4 = vnext4;
            }
            sa0 = sp0; sa1 = sp1; i = inext; si = sin_;
        }
    }
    __syncthreads();

    // ---------- final: z_out = arccos(clip(-V.v0))/pi ----------
    {
        const int r   = t >> 5;
        const int kk2 = t & 31;
        float v0k = v0_lds[kk2];
        const float c1 = (float)(1.0 - 1e-7);
        #pragma unroll 1
        for (int it = 0; it < 25; ++it) {
            int n = 1 + it * 16 + r;   // 1..400
            float d = V_lds[n * Kk + kk2] * v0k;
            d += __shfl_xor(d, 1, 32); d += __shfl_xor(d, 2, 32);
            d += __shfl_xor(d, 4, 32); d += __shfl_xor(d, 8, 32);
            d += __shfl_xor(d, 16, 32);
            if (kk2 == 0) {
                float x = -d;
                x = fminf(fmaxf(x, -c1), c1);
                float zo = acosf(x) / PI_F;
                if (inp_lds[n]) zo = z_lds[n];
                out[b * NVv + (n - 1)] = zo;
            }
        }
    }
}

extern "C" void kernel_launch(void* const* d_in, const int* in_sizes, int n_in,
                              void* d_out, int out_size, void* d_ws, size_t ws_size,
                              hipStream_t stream) {
    const float* S     = (const float*)d_in[0];
    const float* z     = (const float*)d_in[1];
    const int*   isin  = (const int*)d_in[2];
    const float* Vinit = (const float*)d_in[3];
    const int*   perm  = (const int*)d_in[4];
    float* outp = (float*)d_out;
    hipLaunchKernelGGL(satnet_kernel, dim3(Bb), dim3(NT), 0, stream,
                       S, z, isin, Vinit, perm, outp);
}